// Round 5
// baseline (83.173 us; speedup 1.0000x reference)
//
#include <hip/hip_runtime.h>
#include <hip/hip_bf16.h>

// SwitchLinear: out[b,o] = sum_i x[b,i]*W[o,i,c_b] + bias[o,c_b]
// x,W,bias,out = fp32; idx = int32. B=8192 I=O=256 C=32.
// 2 dispatches: prep (W-transpose->bf16 + channel bucket), then grouped MFMA
// GEMM which converts fp32 x -> bf16 inline during A-tile staging.
// (R4's cooperative single-dispatch failed at launch validation — reverted.)
#define NB 8192
#define NI 256
#define NO 256
#define NC 32

typedef __attribute__((ext_vector_type(8))) short short8;   // 8 x bf16
typedef __attribute__((ext_vector_type(4))) float floatx4;  // MFMA acc

// ---- workspace layout (bytes) ----
#define WS_COUNTS_OFF 0            // uint counts[NC]
#define WS_LISTS_OFF  (4u << 10)   // ushort lists[NC][NB]
#define WS_WT_OFF     (1u << 20)   // ushort wT[NC][NO][NI]

static __device__ __forceinline__ unsigned short f2bf(float f) {
    __hip_bfloat16 h = __float2bfloat16(f);   // RNE
    return *(unsigned short*)&h;
}

// prep: blocks [0,256) transpose W[o][i][c] fp32 -> wT[c][o][i] bf16;
//       blocks [256,288) bucket channel c = bid-256 (LDS counter).
#define PREP_BLOCKS 288

__global__ __launch_bounds__(256) void k_prep(
        const int* __restrict__ idx,
        const float* __restrict__ w,
        unsigned int* __restrict__ counts,
        unsigned short* __restrict__ lists,
        unsigned short* __restrict__ wT) {
    const int bid = blockIdx.x;
    const int tid = threadIdx.x;

    if (bid < 256) {
        int g = bid * 256 + tid;   // g = o*NI + i, 0..65535
        const float4* src = (const float4*)(w + (size_t)g * NC);
        unsigned short vals[NC];
#pragma unroll
        for (int s = 0; s < 8; ++s) {
            float4 v = src[s];
            vals[s * 4 + 0] = f2bf(v.x);
            vals[s * 4 + 1] = f2bf(v.y);
            vals[s * 4 + 2] = f2bf(v.z);
            vals[s * 4 + 3] = f2bf(v.w);
        }
#pragma unroll
        for (int c = 0; c < NC; ++c) {
            // fixed c: 64 consecutive g per wave -> 128 B contiguous store
            wT[(size_t)c * (NO * NI) + g] = vals[c];
        }
    } else {
        __shared__ unsigned int lcnt;
        const int c = bid - 256;
        if (tid == 0) lcnt = 0u;
        __syncthreads();
        const int4* idx4 = (const int4*)idx;
        for (int t = tid; t < NB / 4; t += 256) {
            int4 v = idx4[t];
            int b0 = t * 4;
            if (v.x == c) lists[c * NB + atomicAdd(&lcnt, 1u)] = (unsigned short)(b0 + 0);
            if (v.y == c) lists[c * NB + atomicAdd(&lcnt, 1u)] = (unsigned short)(b0 + 1);
            if (v.z == c) lists[c * NB + atomicAdd(&lcnt, 1u)] = (unsigned short)(b0 + 2);
            if (v.w == c) lists[c * NB + atomicAdd(&lcnt, 1u)] = (unsigned short)(b0 + 3);
        }
        __syncthreads();
        if (tid == 0) counts[c] = lcnt;
    }
}

// Grouped GEMM: grid (c, o-tile, z=8), block = 256 = 4 waves, persistent in m.
// Tile M=64 (gathered rows), N=64 outputs, K streamed 2 x 128 (bf16 LDS).
// A-tile: fp32 global loads (2 x float4/lane) converted to bf16 in-register.
// LDS rows padded to 136 bf16 (272 B, 16B-aligned; 68 dw == 4 mod 32 -> 2-way free).
__launch_bounds__(256)
__global__ void k_gemm(const float* __restrict__ x,
                       const unsigned short* __restrict__ wT,
                       const float* __restrict__ bias,
                       const unsigned int* __restrict__ counts,
                       const unsigned short* __restrict__ lists,
                       float* __restrict__ out) {
    const int c  = blockIdx.x;
    const int o0 = blockIdx.y * 64;
    const int cnt = (int)counts[c];

    __shared__ unsigned short As[64][136];
    __shared__ unsigned short Bs[64][136];
    __shared__ int blist[64];

    const int tid  = threadIdx.x;
    const int wv   = tid >> 6;
    const int lane = tid & 63;
    const int lrc  = lane & 15;        // A row m / B,D col n
    const int koff = (lane >> 4) * 8;  // k offset within 32-chunk
    const int rbase = (lane >> 4) * 4;

    const unsigned short* wTc = wT + ((size_t)c * NO + o0) * NI;
    const int o = o0 + wv * 16 + lrc;
    const float bv = bias[o * NC + c];

    for (int mt = blockIdx.z; mt * 64 < cnt; mt += 8) {
        const int m0 = mt * 64;
        if (tid < 64) {
            int mr = m0 + tid;
            blist[tid] = (int)lists[c * NB + (mr < cnt ? mr : m0)];
        }
        __syncthreads();

        floatx4 acc[4];
#pragma unroll
        for (int ms = 0; ms < 4; ++ms) acc[ms] = (floatx4){0.f, 0.f, 0.f, 0.f};

#pragma unroll
        for (int kt = 0; kt < 2; ++kt) {
            const int kb = kt * 128;
#pragma unroll
            for (int s = 0; s < 4; ++s) {
                int lin = tid + s * 256;   // 64 rows x 8 segs of 8 elems
                int row = lin >> 4;
                int c8  = (lin & 15) * 8;
                // A: fp32 -> bf16 inline
                const float4* pa = (const float4*)(x + (size_t)blist[row] * NI + kb + c8);
                float4 a0 = pa[0], a1 = pa[1];
                unsigned short r[8];
                r[0] = f2bf(a0.x); r[1] = f2bf(a0.y); r[2] = f2bf(a0.z); r[3] = f2bf(a0.w);
                r[4] = f2bf(a1.x); r[5] = f2bf(a1.y); r[6] = f2bf(a1.z); r[7] = f2bf(a1.w);
                *(uint4*)&As[row][c8] = *(uint4*)r;
                // B: bf16 straight copy
                *(uint4*)&Bs[row][c8] = *(const uint4*)(wTc + (size_t)row * NI + kb + c8);
            }
            __syncthreads();

            const int n0 = wv * 16;
#pragma unroll
            for (int k0 = 0; k0 < 4; ++k0) {
                short8 bfrag = *(const short8*)&Bs[n0 + lrc][k0 * 32 + koff];
#pragma unroll
                for (int ms = 0; ms < 4; ++ms) {
                    short8 afrag = *(const short8*)&As[ms * 16 + lrc][k0 * 32 + koff];
                    acc[ms] = __builtin_amdgcn_mfma_f32_16x16x32_bf16(afrag, bfrag, acc[ms], 0, 0, 0);
                }
            }
            __syncthreads();
        }

        // D layout: col = lane&15, row = (lane>>4)*4 + reg
#pragma unroll
        for (int ms = 0; ms < 4; ++ms) {
#pragma unroll
            for (int r = 0; r < 4; ++r) {
                int row = ms * 16 + rbase + r;
                if (m0 + row < cnt) {
                    out[(size_t)blist[row] * NO + o] = acc[ms][r] + bv;
                }
            }
        }
        __syncthreads();   // protect blist/As/Bs for next persistent iteration
    }
}

extern "C" void kernel_launch(void* const* d_in, const int* in_sizes, int n_in,
                              void* d_out, int out_size, void* d_ws, size_t ws_size,
                              hipStream_t stream) {
    const float* x    = (const float*)d_in[0];   // fp32 [NB][NI]
    const int*   idx  = (const int*)d_in[1];     // int32 [NB]
    const float* w    = (const float*)d_in[2];   // fp32 [NO][NI][NC]
    const float* bias = (const float*)d_in[3];   // fp32 [NO][NC]
    float* out = (float*)d_out;                  // fp32 [NB][NO]

    char* ws = (char*)d_ws;
    unsigned int*   counts = (unsigned int*)(ws + WS_COUNTS_OFF);
    unsigned short* lists  = (unsigned short*)(ws + WS_LISTS_OFF);
    unsigned short* wT     = (unsigned short*)(ws + WS_WT_OFF);

    k_prep<<<PREP_BLOCKS, 256, 0, stream>>>(idx, w, counts, lists, wT);
    dim3 grid(NC, NO / 64, 8);
    k_gemm<<<grid, 256, 0, stream>>>(x, wT, bias, counts, lists, out);
}